// Round 14
// baseline (50519.629 us; speedup 1.0000x reference)
//
#include <hip/hip_runtime.h>
#include <cmath>

#define VOCAB   4096
#define ENC_DIM 1024
#define PRED_H  640
#define JOINT_H 640
#define TMAX    128
#define MAX_SYM 30
#define NSTEPS  (TMAX*(MAX_SYM+1))   // 3968
#define NWG     160
#define NTHR    512
#define RLX __ATOMIC_RELAXED
#define AGT __HIP_MEMORY_SCOPE_AGENT

typedef unsigned long long u64;
typedef __attribute__((ext_vector_type(4))) unsigned int u32x4;

// ws layout (bytes), one 64B line per WG per exchange:
//   0      dataA[160 lines]  line w = 4 tagged u64 (h0n[4w+j]), j-th written by wave j
//   10240  dataB[160 lines]  (h1n)
//   20480  dataH[160 lines]  (hid)
//   30720  parts[160 lines]  line w = 8 tagged argmax entries, one per wave
// tagged u64 = (tag<<32)|f32  (data) ; entries: key<<24 | tag12<<12 | (4095-r)

__device__ __forceinline__ float wave_red(float v){
  v += __shfl_xor(v, 32, 64);
  v += __shfl_xor(v, 16, 64);
  v += __shfl_xor(v,  8, 64);
  v += __shfl_xor(v,  4, 64);
  v += __shfl_xor(v,  2, 64);
  v += __shfl_xor(v,  1, 64);
  return v;
}

__device__ __forceinline__ float sigf(float x){ return 1.0f/(1.0f+expf(-x)); }

__device__ __forceinline__ void send8(u64* base, int w, int slot, float v, unsigned tag){
  __hip_atomic_store(base + ((size_t)w<<3) + slot,
                     ((u64)tag<<32) | (u64)__float_as_uint(v), RLX, AGT);
}

// consumer thread i: one-shot 32B self-validating read of line i (4 tagged u64)
__device__ __forceinline__ void pollline(const u64* base, float* dstLDS,
                                         unsigned tag, int i){
  const u64* p = base + ((size_t)i<<3);
  u32x4 v0, v1;
  for(;;){
    asm volatile("global_load_dwordx4 %0, %2, off sc0 sc1\n\t"
                 "global_load_dwordx4 %1, %3, off sc0 sc1\n\t"
                 "s_waitcnt vmcnt(0)"
                 : "=&v"(v0), "=&v"(v1) : "v"(p), "v"(p+2) : "memory");
    if (v0.y == tag && v0.w == tag && v1.y == tag && v1.w == tag) break;
    __builtin_amdgcn_s_sleep(1);
  }
  __builtin_amdgcn_sched_barrier(0);
  float* d = dstLDS + (i<<2);
  d[0] = __uint_as_float(v0.x);
  d[1] = __uint_as_float(v0.z);
  d[2] = __uint_as_float(v1.x);
  d[3] = __uint_as_float(v1.z);
}

// consumer thread i: 64B read of parts line i (8 entries), returns local max
__device__ __forceinline__ u64 pollparts(const u64* base, unsigned tag12, int i){
  const u64* p = base + ((size_t)i<<3);
  u32x4 v0, v1, v2, v3;
  for(;;){
    asm volatile("global_load_dwordx4 %0, %4, off sc0 sc1\n\t"
                 "global_load_dwordx4 %1, %5, off sc0 sc1\n\t"
                 "global_load_dwordx4 %2, %6, off sc0 sc1\n\t"
                 "global_load_dwordx4 %3, %7, off sc0 sc1\n\t"
                 "s_waitcnt vmcnt(0)"
                 : "=&v"(v0),"=&v"(v1),"=&v"(v2),"=&v"(v3)
                 : "v"(p),"v"(p+2),"v"(p+4),"v"(p+6) : "memory");
    bool ok = (((v0.x>>12)&0xFFFu)==tag12) & (((v0.z>>12)&0xFFFu)==tag12)
            & (((v1.x>>12)&0xFFFu)==tag12) & (((v1.z>>12)&0xFFFu)==tag12)
            & (((v2.x>>12)&0xFFFu)==tag12) & (((v2.z>>12)&0xFFFu)==tag12)
            & (((v3.x>>12)&0xFFFu)==tag12) & (((v3.z>>12)&0xFFFu)==tag12);
    if (ok) break;
    __builtin_amdgcn_s_sleep(1);
  }
  u64 m = ((u64)v0.y<<32)|v0.x, e;
  e = ((u64)v0.w<<32)|v0.z; if (e>m) m=e;
  e = ((u64)v1.y<<32)|v1.x; if (e>m) m=e;
  e = ((u64)v1.w<<32)|v1.z; if (e>m) m=e;
  e = ((u64)v2.y<<32)|v2.x; if (e>m) m=e;
  e = ((u64)v2.w<<32)|v2.z; if (e>m) m=e;
  e = ((u64)v3.y<<32)|v3.x; if (e>m) m=e;
  e = ((u64)v3.w<<32)|v3.z; if (e>m) m=e;
  return m;
}

__device__ __forceinline__ u64 mkentry(float lg, int r, unsigned ep){
  unsigned u = __float_as_uint(lg);
  u = (u & 0x80000000u) ? ~u : (u | 0x80000000u);
  return ((u64)u<<24) | ((u64)(ep&0xFFFu)<<12) | (u64)(4095 - r);
}

__global__ void init_ws(unsigned* ws){
  for (int i = threadIdx.x; i < 10240; i += 256) ws[i] = 0u;   // 40960 B
}

__global__ __launch_bounds__(NTHR, 1)
void rnnt_decode(const float* __restrict__ enc,
                 const int*   __restrict__ outlen_p,
                 const float* __restrict__ emb,
                 const float* __restrict__ Wih0, const float* __restrict__ Whh0, const float* __restrict__ b0,
                 const float* __restrict__ Wih1, const float* __restrict__ Whh1, const float* __restrict__ b1,
                 const float* __restrict__ Wj1,  const float* __restrict__ bj1,
                 const float* __restrict__ Wj2,  const float* __restrict__ bj2,
                 float* __restrict__ out,
                 char* __restrict__ ws)
{
  const int wg = blockIdx.x, tid = threadIdx.x;
  const int wave = tid >> 6, lane = tid & 63;
  const int timesteps = outlen_p[0];

  u64* dataA = (u64*)(ws);
  u64* dataB = (u64*)(ws + 10240);
  u64* dataH = (u64*)(ws + 20480);
  u64* parts = (u64*)(ws + 30720);

  __shared__ float xsh[ENC_DIM];
  __shared__ float h0buf[PRED_H];
  __shared__ float h1buf[PRED_H];
  __shared__ float hidsh[JOINT_H];
  __shared__ float zsh[4][4];
  __shared__ float zjsA[8], zjsB[8];
  __shared__ float c0c[4], c1c[4], c0p[4], c1p[4];
  __shared__ float bj1sh[4];
  __shared__ u64 pmx[3];

  const int jb = wg*4;                    // uniform: 4 j per WG (640/160)
  const int pollid = tid - 256;           // poller waves 4-6: pollid in [0,160)
  const bool isPoll = ((unsigned)pollid < 160u);

  // ---- LSTM rows: 16 per WG; wave -> gate gA=wave&3, j's jA=wave>>2 and jA+2
  const int gA = wave & 3;
  const int jA = wave >> 2;               // 0..1
  const int rowA = gA*PRED_H + jb + jA;
  const int rowB = gA*PRED_H + jb + jA + 2;

  float w0xA[10], w0hA[10], w0xB[10], w0hB[10];
  float w1xA[10], w1hA[10], w1xB[10], w1hB[10];
  #pragma unroll
  for (int i = 0; i < 10; ++i){
    int c = lane + (i<<6);
    w0xA[i] = Wih0[(size_t)rowA*PRED_H + c];
    w0hA[i] = Whh0[(size_t)rowA*PRED_H + c];
    w1xA[i] = Wih1[(size_t)rowA*PRED_H + c];
    w1hA[i] = Whh1[(size_t)rowA*PRED_H + c];
    w0xB[i] = Wih0[(size_t)rowB*PRED_H + c];
    w0hB[i] = Whh0[(size_t)rowB*PRED_H + c];
    w1xB[i] = Wih1[(size_t)rowB*PRED_H + c];
    w1hB[i] = Whh1[(size_t)rowB*PRED_H + c];
  }
  const float bA0 = b0[rowA], bA1 = b1[rowA];
  const float bB0 = b0[rowB], bB1 = b1[rowB];

  // ---- Joint1: 4 rows; 2 groups x 2 passes (identical mapping to R13)
  const int grp = wave >> 2;
  const int vt  = ((wave & 3)<<6) | lane; // 0..255
  const int rP0 = jb + grp;
  const int rP1 = jb + 2 + grp;
  float wjf0[4], wjh0[3], wjf1[4], wjh1[3];
  #pragma unroll
  for (int i = 0; i < 4; ++i){
    wjf0[i] = Wj1[(size_t)rP0*(ENC_DIM+PRED_H) + vt + (i<<8)];
    wjf1[i] = Wj1[(size_t)rP1*(ENC_DIM+PRED_H) + vt + (i<<8)];
  }
  #pragma unroll
  for (int i = 0; i < 3; ++i){
    int c = vt + (i<<8);
    wjh0[i] = (c < PRED_H) ? Wj1[(size_t)rP0*(ENC_DIM+PRED_H) + ENC_DIM + c] : 0.f;
    wjh1[i] = (c < PRED_H) ? Wj1[(size_t)rP1*(ENC_DIM+PRED_H) + ENC_DIM + c] : 0.f;
  }
  float ca0 = 0.f, ca1 = 0.f;

  // ---- Joint2: 25/26 rows per WG (identical to R13)
  const int nrows = (wg < 96) ? 26 : 25;
  const int r2b = wg*25 + (wg < 96 ? wg : 96);
  float wj2[4][10], bj2r[4];
  #pragma unroll
  for (int p = 0; p < 4; ++p){
    bool act = (p*8 + wave) < nrows;
    int r = act ? (r2b + p*8 + wave) : 0;
    #pragma unroll
    for (int i = 0; i < 10; ++i)
      wj2[p][i] = act ? Wj2[(size_t)r*JOINT_H + lane + (i<<6)] : 0.f;
    bj2r[p] = act ? bj2[r] : 0.f;
  }

  for (int i = tid; i < PRED_H; i += NTHR){ h0buf[i] = 0.f; h1buf[i] = 0.f; }
  if (tid < 4){ c0c[tid] = 0.f; c1c[tid] = 0.f; bj1sh[tid] = bj1[jb+tid]; }
  __syncthreads();

  int t = 0, sa = 0, last = -1, cnt = 0, tStaged = -1;
  bool done = false, reuse = false;
  float s0A = 0.f, s0B = 0.f, s1A = 0.f, s1B = 0.f;   // speculative Whh sums

  for (int s = 0; s < NSTEPS; ++s){
    if (done){
      if (wg < 8) out[(size_t)s*VOCAB + wg*NTHR + tid] = 0.f;
      continue;
    }
    const unsigned tag = (unsigned)(s + 1);

    if (!reuse){
      // ===== A: x-chain only (h-part speculated in prior D) =====
      {
        float XA = 0.f, XB = 0.f;
        if (last >= 0){
          float xr[10];
          #pragma unroll
          for (int i = 0; i < 10; ++i)
            xr[i] = emb[(size_t)last*PRED_H + lane + (i<<6)];
          #pragma unroll
          for (int i = 0; i < 10; ++i){
            XA = fmaf(w0xA[i], xr[i], XA);
            XB = fmaf(w0xB[i], xr[i], XB);
          }
          XA = wave_red(XA);
          XB = wave_red(XB);
        }
        if (lane == 0){
          zsh[gA][jA]   = XA + s0A + bA0;
          zsh[gA][jA+2] = XB + s0B + bB0;
        }
      }
      __syncthreads();                    // zsh ready (also orders E's c-copies)
      if (wave < 4 && lane == 0){         // gate-wave j: compute + own 8B send
        int j = wave;
        float ig = sigf(zsh[0][j]), fg = sigf(zsh[1][j]);
        float gg = tanhf(zsh[2][j]), og = sigf(zsh[3][j]);
        float c2 = fg*c0c[j] + ig*gg;
        c0p[j] = c2;
        send8(dataA, wg, j, og*tanhf(c2), tag);
      }

      // ===== B: pollers (waves 4-6) fetch h0n in parallel with A-sends =====
      if (isPoll) pollline(dataA, h0buf, tag, pollid);
      __syncthreads();
      {
        float XA = 0.f, XB = 0.f;
        #pragma unroll
        for (int i = 0; i < 10; ++i){
          float h0 = h0buf[lane+(i<<6)];
          XA = fmaf(w1xA[i], h0, XA);
          XB = fmaf(w1xB[i], h0, XB);
        }
        XA = wave_red(XA);
        XB = wave_red(XB);
        if (lane == 0){
          zsh[gA][jA]   = XA + s1A + bA1;
          zsh[gA][jA+2] = XB + s1B + bB1;
        }
      }
      __syncthreads();
      if (wave < 4 && lane == 0){
        int j = wave;
        float ig = sigf(zsh[0][j]), fg = sigf(zsh[1][j]);
        float gg = tanhf(zsh[2][j]), og = sigf(zsh[3][j]);
        float c2 = fg*c1c[j] + ig*gg;
        c1p[j] = c2;
        send8(dataB, wg, j, og*tanhf(c2), tag);
      }
    }

    // ===== C: joint hidden =====
    {
      int tcap = (t < TMAX-1) ? t : (TMAX-1);
      bool fNew = (tcap != tStaged);
      if (fNew && tid < 256)
        for (int i = tid; i < ENC_DIM; i += 256) xsh[i] = enc[(size_t)tcap*ENC_DIM + i];
      if (!reuse && isPoll) pollline(dataB, h1buf, tag, pollid);
      __syncthreads();
      if (fNew){
        float a = 0.f, b = 0.f;
        #pragma unroll
        for (int i = 0; i < 4; ++i){
          a = fmaf(wjf0[i], xsh[vt+(i<<8)], a);
          b = fmaf(wjf1[i], xsh[vt+(i<<8)], b);
        }
        ca0 = a; ca1 = b;
        tStaged = tcap;
      }
      {
        float acc = ca0;
        #pragma unroll
        for (int i = 0; i < 3; ++i){
          int c = vt + (i<<8);
          acc = fmaf(wjh0[i], h1buf[(c < PRED_H) ? c : 0], acc);
        }
        acc = wave_red(acc);
        if (lane == 0) zjsA[wave] = acc;
        float acc2 = ca1;
        #pragma unroll
        for (int i = 0; i < 3; ++i){
          int c = vt + (i<<8);
          acc2 = fmaf(wjh1[i], h1buf[(c < PRED_H) ? c : 0], acc2);
        }
        acc2 = wave_red(acc2);
        if (lane == 0) zjsB[wave] = acc2;
      }
      __syncthreads();
      if (wave < 4 && lane == 0){         // relu-wave j: own 8B send
        int j = wave;
        float v;
        if (j == 0)      v = zjsA[0]+zjsA[1]+zjsA[2]+zjsA[3] + bj1sh[0];
        else if (j == 1) v = zjsA[4]+zjsA[5]+zjsA[6]+zjsA[7] + bj1sh[1];
        else if (j == 2) v = zjsB[0]+zjsB[1]+zjsB[2]+zjsB[3] + bj1sh[2];
        else             v = zjsB[4]+zjsB[5]+zjsB[6]+zjsB[7] + bj1sh[3];
        send8(dataH, wg, j, v > 0.f ? v : 0.f, tag);
      }
    }

    // ===== D: logits + argmax (per-wave parts entries; spec in the wait) =====
    int k;
    {
      if (isPoll) pollline(dataH, hidsh, tag, pollid);
      __syncthreads();
      {
        float a0 = 0.f, a1 = 0.f, a2 = 0.f, a3 = 0.f;
        #pragma unroll
        for (int i = 0; i < 10; ++i){
          float h = hidsh[lane+(i<<6)];
          a0 = fmaf(wj2[0][i], h, a0);
          a1 = fmaf(wj2[1][i], h, a1);
          a2 = fmaf(wj2[2][i], h, a2);
          a3 = fmaf(wj2[3][i], h, a3);
        }
        a0 = wave_red(a0); a1 = wave_red(a1);
        a2 = wave_red(a2); a3 = wave_red(a3);
        if (lane == 0){
          u64 best = 0;
          float av[4] = {a0, a1, a2, a3};
          #pragma unroll
          for (int p = 0; p < 4; ++p){
            if (p*8 + wave < nrows){
              int r = r2b + p*8 + wave;
              float lg = av[p] + bj2r[p];
              out[(size_t)s*VOCAB + r] = lg;
              u64 e = mkentry(lg, r, tag);
              if (e > best) best = e;
            }
          }
          __hip_atomic_store(&parts[((size_t)wg<<3) + wave], best, RLX, AGT);
        }
      }

      // ---- speculative Whh chains on fresh h0/h1 (consumed on next emit) ----
      {
        float a0 = 0.f, b0v = 0.f, a1 = 0.f, b1v = 0.f;
        #pragma unroll
        for (int i = 0; i < 10; ++i){
          float h0p = h0buf[lane+(i<<6)];
          float h1p = h1buf[lane+(i<<6)];
          a0  = fmaf(w0hA[i], h0p, a0);
          b0v = fmaf(w0hB[i], h0p, b0v);
          a1  = fmaf(w1hA[i], h1p, a1);
          b1v = fmaf(w1hB[i], h1p, b1v);
        }
        s0A = wave_red(a0);  s0B = wave_red(b0v);
        s1A = wave_red(a1);  s1B = wave_red(b1v);
      }

      // ---- gather: thread i reads parts line i (8 entries, self-validating) ----
      u64 myp = 0;
      if (tid < 160) myp = pollparts(parts, tag & 0xFFFu, tid);
      if (wave < 3){
        #pragma unroll
        for (int off = 32; off; off >>= 1){
          u64 o = __shfl_xor(myp, off, 64);
          if (o > myp) myp = o;
        }
        if (lane == 0) pmx[wave] = myp;
      }
      __syncthreads();
      u64 m = pmx[0];
      if (pmx[1] > m) m = pmx[1];
      if (pmx[2] > m) m = pmx[2];
      k = 4095 - (int)(m & 0xFFFull);
    }

    // ===== E: decision (replicated; no trailing barrier needed) =====
    bool stop = (k == 0) || (sa >= MAX_SYM);
    if (!stop){
      if (wg == 0 && tid == 0) out[(size_t)NSTEPS*VOCAB + cnt] = (float)k;
      if (tid < 4){ c0c[tid] = c0p[tid]; c1c[tid] = c1p[tid]; }
      cnt++; sa++; last = k; reuse = false;
    } else {
      sa = 0; t++; reuse = true;
      if (t >= timesteps) done = true;
    }
  }

  // labels tail (-1) and cnt
  size_t lab = (size_t)NSTEPS*VOCAB;
  int gidx = wg*NTHR + tid;
  for (int i = cnt + gidx; i < NSTEPS; i += NWG*NTHR) out[lab + i] = -1.f;
  if (wg == 0 && tid == 0) out[lab + NSTEPS] = (float)cnt;
}

extern "C" void kernel_launch(void* const* d_in, const int* in_sizes, int n_in,
                              void* d_out, int out_size, void* d_ws, size_t ws_size,
                              hipStream_t stream) {
  const float* enc  = (const float*)d_in[0];
  const int*   olen = (const int*)  d_in[1];
  const float* emb  = (const float*)d_in[2];
  const float* Wih0 = (const float*)d_in[3];
  const float* Whh0 = (const float*)d_in[4];
  const float* b0   = (const float*)d_in[5];
  const float* Wih1 = (const float*)d_in[6];
  const float* Whh1 = (const float*)d_in[7];
  const float* b1   = (const float*)d_in[8];
  const float* Wj1  = (const float*)d_in[9];
  const float* bj1  = (const float*)d_in[10];
  const float* Wj2  = (const float*)d_in[11];
  const float* bj2  = (const float*)d_in[12];
  float* out = (float*)d_out;
  char* ws = (char*)d_ws;

  init_ws<<<1, 256, 0, stream>>>((unsigned*)d_ws);

  void* args[] = {&enc,&olen,&emb,&Wih0,&Whh0,&b0,&Wih1,&Whh1,&b1,
                  &Wj1,&bj1,&Wj2,&bj2,&out,&ws};
  hipLaunchCooperativeKernel((const void*)rnnt_decode, dim3(NWG), dim3(NTHR),
                             args, 0, stream);
}

// Round 15
// 40993.610 us; speedup vs baseline: 1.2324x; 1.2324x over previous
//
#include <hip/hip_runtime.h>
#include <cmath>

#define VOCAB   4096
#define ENC_DIM 1024
#define PRED_H  640
#define JOINT_H 640
#define TMAX    128
#define MAX_SYM 30
#define NSTEPS  (TMAX*(MAX_SYM+1))   // 3968
#define NWG     160
#define NTHR    512
#define RLX __ATOMIC_RELAXED
#define AGT __HIP_MEMORY_SCOPE_AGENT

typedef unsigned long long u64;
typedef __attribute__((ext_vector_type(4))) float f32x4;
typedef __attribute__((ext_vector_type(4))) unsigned int u32x4;

// ws layout (bytes), one 64B line per WG per exchange:
//   0      dataA[160 lines]  line w = 4 tagged u64 {h0n[4w+e], tag}  (32B used)
//   10240  dataB[160 lines]  (h1n)
//   20480  dataH[160 lines]  (hid)
//   30720  parts[160 lines]  (tagged u64 argmax entry at line start)
// tagged u64 = (tag u32 << 32) | f32 bits. tag = s+1 (>=1; 0 = unwritten)

__device__ __forceinline__ float wave_red(float v){
  v += __shfl_xor(v, 32, 64);
  v += __shfl_xor(v, 16, 64);
  v += __shfl_xor(v,  8, 64);
  v += __shfl_xor(v,  4, 64);
  v += __shfl_xor(v,  2, 64);
  v += __shfl_xor(v,  1, 64);
  return v;
}

__device__ __forceinline__ float sigf(float x){ return 1.0f/(1.0f+expf(-x)); }

// producer: 4 values + tags as 32B, two back-to-back 16B stores (atomic line fill)
__device__ __forceinline__ void sendline(u64* base, int w, f32x4 hv, unsigned tag){
  u32x4 a, b;
  a.x = __float_as_uint(hv.x); a.y = tag; a.z = __float_as_uint(hv.y); a.w = tag;
  b.x = __float_as_uint(hv.z); b.y = tag; b.z = __float_as_uint(hv.w); b.w = tag;
  u64* p = base + ((size_t)w<<3);
  asm volatile("global_store_dwordx4 %0, %2, off sc0 sc1\n\t"
               "global_store_dwordx4 %1, %3, off sc0 sc1"
               :: "v"(p), "v"(p+2), "v"(a), "v"(b) : "memory");
}

// consumer thread i: one-shot 32B self-validating read
__device__ __forceinline__ void pollline(const u64* base, float* dstLDS,
                                         unsigned tag, int i){
  const u64* p = base + ((size_t)i<<3);
  u32x4 v0, v1;
  for(;;){
    asm volatile("global_load_dwordx4 %0, %2, off sc0 sc1\n\t"
                 "global_load_dwordx4 %1, %3, off sc0 sc1\n\t"
                 "s_waitcnt vmcnt(0)"
                 : "=&v"(v0), "=&v"(v1) : "v"(p), "v"(p+2) : "memory");
    if (v0.y == tag && v0.w == tag && v1.y == tag && v1.w == tag) break;
    __builtin_amdgcn_s_sleep(1);
  }
  __builtin_amdgcn_sched_barrier(0);
  float* d = dstLDS + (i<<2);
  d[0] = __uint_as_float(v0.x);
  d[1] = __uint_as_float(v0.z);
  d[2] = __uint_as_float(v1.x);
  d[3] = __uint_as_float(v1.z);
}

// argmax entry: key(32b order-preserving) << 24 | (tag&0xFFF)<<12 | (4095-r)
__device__ __forceinline__ u64 mkentry(float lg, int r, unsigned ep){
  unsigned u = __float_as_uint(lg);
  u = (u & 0x80000000u) ? ~u : (u | 0x80000000u);
  return ((u64)u<<24) | ((u64)(ep&0xFFFu)<<12) | (u64)(4095 - r);
}

__global__ void init_ws(unsigned* ws){
  for (int i = threadIdx.x; i < 10240; i += 256) ws[i] = 0u;   // 40960 B
}

__global__ __launch_bounds__(NTHR, 1)
void rnnt_decode(const float* __restrict__ enc,
                 const int*   __restrict__ outlen_p,
                 const float* __restrict__ emb,
                 const float* __restrict__ Wih0, const float* __restrict__ Whh0, const float* __restrict__ b0,
                 const float* __restrict__ Wih1, const float* __restrict__ Whh1, const float* __restrict__ b1,
                 const float* __restrict__ Wj1,  const float* __restrict__ bj1,
                 const float* __restrict__ Wj2,  const float* __restrict__ bj2,
                 float* __restrict__ out,
                 char* __restrict__ ws)
{
  const int wg = blockIdx.x, tid = threadIdx.x;
  const int wave = tid >> 6, lane = tid & 63;
  const int timesteps = outlen_p[0];

  u64* dataA = (u64*)(ws);
  u64* dataB = (u64*)(ws + 10240);
  u64* dataH = (u64*)(ws + 20480);
  u64* parts = (u64*)(ws + 30720);

  __shared__ float xsh[ENC_DIM];
  __shared__ float h0buf[PRED_H];
  __shared__ float h1buf[PRED_H];
  __shared__ float hidsh[JOINT_H];
  __shared__ float zsh[4][4];
  __shared__ float zjsA[8], zjsB[8];
  __shared__ float c0c[4], c1c[4], c0p[4], c1p[4];
  __shared__ float bj1sh[4];
  __shared__ u64 psh[8];
  __shared__ u64 pmx[3];

  const int jb = wg*4;                    // uniform: 4 j per WG (640/160)
  const int pollid = tid - 256;           // poller waves 4-6: pollid in [0,160)
  const bool isPoll = ((unsigned)pollid < 160u);

  // ---- LSTM rows: 16 per WG; wave -> gate gA=wave&3, j's jA=wave>>2 and jA+2
  const int gA = wave & 3;
  const int jA = wave >> 2;               // 0..1
  const int rowA = gA*PRED_H + jb + jA;
  const int rowB = gA*PRED_H + jb + jA + 2;

  float w0xA[10], w0hA[10], w0xB[10], w0hB[10];
  float w1xA[10], w1hA[10], w1xB[10], w1hB[10];
  #pragma unroll
  for (int i = 0; i < 10; ++i){
    int c = lane + (i<<6);
    w0xA[i] = Wih0[(size_t)rowA*PRED_H + c];
    w0hA[i] = Whh0[(size_t)rowA*PRED_H + c];
    w1xA[i] = Wih1[(size_t)rowA*PRED_H + c];
    w1hA[i] = Whh1[(size_t)rowA*PRED_H + c];
    w0xB[i] = Wih0[(size_t)rowB*PRED_H + c];
    w0hB[i] = Whh0[(size_t)rowB*PRED_H + c];
    w1xB[i] = Wih1[(size_t)rowB*PRED_H + c];
    w1hB[i] = Whh1[(size_t)rowB*PRED_H + c];
  }
  const float bA0 = b0[rowA], bA1 = b1[rowA];
  const float bB0 = b0[rowB], bB1 = b1[rowB];

  // ---- Joint1: 4 rows; 2 groups x 2 passes (identical to R13)
  const int grp = wave >> 2;
  const int vt  = ((wave & 3)<<6) | lane; // 0..255
  const int rP0 = jb + grp;
  const int rP1 = jb + 2 + grp;
  float wjf0[4], wjh0[3], wjf1[4], wjh1[3];
  #pragma unroll
  for (int i = 0; i < 4; ++i){
    wjf0[i] = Wj1[(size_t)rP0*(ENC_DIM+PRED_H) + vt + (i<<8)];
    wjf1[i] = Wj1[(size_t)rP1*(ENC_DIM+PRED_H) + vt + (i<<8)];
  }
  #pragma unroll
  for (int i = 0; i < 3; ++i){
    int c = vt + (i<<8);
    wjh0[i] = (c < PRED_H) ? Wj1[(size_t)rP0*(ENC_DIM+PRED_H) + ENC_DIM + c] : 0.f;
    wjh1[i] = (c < PRED_H) ? Wj1[(size_t)rP1*(ENC_DIM+PRED_H) + ENC_DIM + c] : 0.f;
  }
  float ca0 = 0.f, ca1 = 0.f;

  // ---- Joint2: 25/26 rows per WG (identical to R13)
  const int nrows = (wg < 96) ? 26 : 25;
  const int r2b = wg*25 + (wg < 96 ? wg : 96);
  float wj2[4][10], bj2r[4];
  #pragma unroll
  for (int p = 0; p < 4; ++p){
    bool act = (p*8 + wave) < nrows;
    int r = act ? (r2b + p*8 + wave) : 0;
    #pragma unroll
    for (int i = 0; i < 10; ++i)
      wj2[p][i] = act ? Wj2[(size_t)r*JOINT_H + lane + (i<<6)] : 0.f;
    bj2r[p] = act ? bj2[r] : 0.f;
  }

  for (int i = tid; i < PRED_H; i += NTHR){ h0buf[i] = 0.f; h1buf[i] = 0.f; }
  if (tid < 4){ c0c[tid] = 0.f; c1c[tid] = 0.f; bj1sh[tid] = bj1[jb+tid]; }
  __syncthreads();

  int t = 0, sa = 0, last = -1, cnt = 0, tStaged = -1;
  bool done = false, reuse = false;
  float s0A = 0.f, s0B = 0.f, s1A = 0.f, s1B = 0.f;   // speculative Whh sums

  for (int s = 0; s < NSTEPS; ++s){
    if (done){
      if (wg < 8) out[(size_t)s*VOCAB + wg*NTHR + tid] = 0.f;
      continue;
    }
    const unsigned tag = (unsigned)(s + 1);

    if (!reuse){
      // ===== A: x-chain only (h-part speculated in prior D) =====
      {
        float XA = 0.f, XB = 0.f;
        if (last >= 0){
          float xr[10];
          #pragma unroll
          for (int i = 0; i < 10; ++i)
            xr[i] = emb[(size_t)last*PRED_H + lane + (i<<6)];
          #pragma unroll
          for (int i = 0; i < 10; ++i){
            XA = fmaf(w0xA[i], xr[i], XA);
            XB = fmaf(w0xB[i], xr[i], XB);
          }
          XA = wave_red(XA);
          XB = wave_red(XB);
        }
        if (lane == 0){
          zsh[gA][jA]   = XA + s0A + bA0;
          zsh[gA][jA+2] = XB + s0B + bB0;
        }
      }
      __syncthreads();
      if (wave == 0){
        float hv = 0.f;
        if (lane < 4){
          float ig = sigf(zsh[0][lane]), fg = sigf(zsh[1][lane]);
          float gg = tanhf(zsh[2][lane]), og = sigf(zsh[3][lane]);
          float c2 = fg*c0c[lane] + ig*gg;
          c0p[lane] = c2;
          hv = og*tanhf(c2);
        }
        f32x4 v;
        v.x = __shfl(hv, 0, 64); v.y = __shfl(hv, 1, 64);
        v.z = __shfl(hv, 2, 64); v.w = __shfl(hv, 3, 64);
        if (lane == 0) sendline(dataA, wg, v, tag);
      }

      // ===== B: poller waves 4-6 fetch h0n concurrently with wave0's send =====
      if (isPoll) pollline(dataA, h0buf, tag, pollid);
      __syncthreads();
      {
        float XA = 0.f, XB = 0.f;
        #pragma unroll
        for (int i = 0; i < 10; ++i){
          float h0 = h0buf[lane+(i<<6)];
          XA = fmaf(w1xA[i], h0, XA);
          XB = fmaf(w1xB[i], h0, XB);
        }
        XA = wave_red(XA);
        XB = wave_red(XB);
        if (lane == 0){
          zsh[gA][jA]   = XA + s1A + bA1;
          zsh[gA][jA+2] = XB + s1B + bB1;
        }
      }
      __syncthreads();
      if (wave == 0){
        float hv = 0.f;
        if (lane < 4){
          float ig = sigf(zsh[0][lane]), fg = sigf(zsh[1][lane]);
          float gg = tanhf(zsh[2][lane]), og = sigf(zsh[3][lane]);
          float c2 = fg*c1c[lane] + ig*gg;
          c1p[lane] = c2;
          hv = og*tanhf(c2);
        }
        f32x4 v;
        v.x = __shfl(hv, 0, 64); v.y = __shfl(hv, 1, 64);
        v.z = __shfl(hv, 2, 64); v.w = __shfl(hv, 3, 64);
        if (lane == 0) sendline(dataB, wg, v, tag);
      }
    }

    // ===== C: joint hidden (4 rows, 2 passes) =====
    {
      int tcap = (t < TMAX-1) ? t : (TMAX-1);
      bool fNew = (tcap != tStaged);
      if (fNew)
        for (int i = tid; i < ENC_DIM; i += NTHR) xsh[i] = enc[(size_t)tcap*ENC_DIM + i];
      if (!reuse){
        if (isPoll) pollline(dataB, h1buf, tag, pollid);
      }
      __syncthreads();
      if (fNew){
        float a = 0.f, b = 0.f;
        #pragma unroll
        for (int i = 0; i < 4; ++i){
          a = fmaf(wjf0[i], xsh[vt+(i<<8)], a);
          b = fmaf(wjf1[i], xsh[vt+(i<<8)], b);
        }
        ca0 = a; ca1 = b;
        tStaged = tcap;
      }
      {
        float acc = ca0;
        #pragma unroll
        for (int i = 0; i < 3; ++i){
          int c = vt + (i<<8);
          acc = fmaf(wjh0[i], h1buf[(c < PRED_H) ? c : 0], acc);
        }
        acc = wave_red(acc);
        if (lane == 0) zjsA[wave] = acc;
        float acc2 = ca1;
        #pragma unroll
        for (int i = 0; i < 3; ++i){
          int c = vt + (i<<8);
          acc2 = fmaf(wjh1[i], h1buf[(c < PRED_H) ? c : 0], acc2);
        }
        acc2 = wave_red(acc2);
        if (lane == 0) zjsB[wave] = acc2;
      }
      __syncthreads();
      if (wave == 0){
        float hv = 0.f;
        if (lane < 4){
          float v;
          if (lane == 0)      v = zjsA[0]+zjsA[1]+zjsA[2]+zjsA[3] + bj1sh[0];
          else if (lane == 1) v = zjsA[4]+zjsA[5]+zjsA[6]+zjsA[7] + bj1sh[1];
          else if (lane == 2) v = zjsB[0]+zjsB[1]+zjsB[2]+zjsB[3] + bj1sh[2];
          else                v = zjsB[4]+zjsB[5]+zjsB[6]+zjsB[7] + bj1sh[3];
          hv = v > 0.f ? v : 0.f;
        }
        f32x4 v;
        v.x = __shfl(hv, 0, 64); v.y = __shfl(hv, 1, 64);
        v.z = __shfl(hv, 2, 64); v.w = __shfl(hv, 3, 64);
        if (lane == 0) sendline(dataH, wg, v, tag);
      }
    }

    // ===== D: logits (single-pass 4-accum) + argmax; spec in the wait =====
    int k;
    {
      if (isPoll) pollline(dataH, hidsh, tag, pollid);
      __syncthreads();
      {
        float a0 = 0.f, a1 = 0.f, a2 = 0.f, a3 = 0.f;
        #pragma unroll
        for (int i = 0; i < 10; ++i){
          float h = hidsh[lane+(i<<6)];
          a0 = fmaf(wj2[0][i], h, a0);
          a1 = fmaf(wj2[1][i], h, a1);
          a2 = fmaf(wj2[2][i], h, a2);
          a3 = fmaf(wj2[3][i], h, a3);
        }
        a0 = wave_red(a0); a1 = wave_red(a1);
        a2 = wave_red(a2); a3 = wave_red(a3);
        if (lane == 0){
          u64 best = 0;
          float av[4] = {a0, a1, a2, a3};
          #pragma unroll
          for (int p = 0; p < 4; ++p){
            if (p*8 + wave < nrows){
              int r = r2b + p*8 + wave;
              float lg = av[p] + bj2r[p];
              out[(size_t)s*VOCAB + r] = lg;
              u64 e = mkentry(lg, r, tag);
              if (e > best) best = e;
            }
          }
          psh[wave] = best;
        }
      }
      __syncthreads();
      if (tid == 0){
        u64 m = psh[0];
        #pragma unroll
        for (int w = 1; w < 8; ++w) if (psh[w] > m) m = psh[w];
        __hip_atomic_store(&parts[(size_t)wg<<3], m, RLX, AGT);
      }

      // ---- speculative Whh chains on fresh h0/h1 (consumed on next emit) ----
      {
        float a0 = 0.f, b0v = 0.f, a1 = 0.f, b1v = 0.f;
        #pragma unroll
        for (int i = 0; i < 10; ++i){
          float h0p = h0buf[lane+(i<<6)];
          float h1p = h1buf[lane+(i<<6)];
          a0  = fmaf(w0hA[i], h0p, a0);
          b0v = fmaf(w0hB[i], h0p, b0v);
          a1  = fmaf(w1hA[i], h1p, a1);
          b1v = fmaf(w1hB[i], h1p, b1v);
        }
        s0A = wave_red(a0);  s0B = wave_red(b0v);
        s1A = wave_red(a1);  s1B = wave_red(b1v);
      }

      // ---- all-WG gather of 160 tagged partials (64B stride) ----
      u64 myp = 0;
      if (tid < 160){
        for(;;){
          u64 e = __hip_atomic_load(&parts[(size_t)tid<<3], RLX, AGT);
          if ((unsigned)((e>>12) & 0xFFFu) == (tag & 0xFFFu)){ myp = e; break; }
          __builtin_amdgcn_s_sleep(1);
        }
      }
      if (wave < 3){
        #pragma unroll
        for (int off = 32; off; off >>= 1){
          u64 o = __shfl_xor(myp, off, 64);
          if (o > myp) myp = o;
        }
        if (lane == 0) pmx[wave] = myp;
      }
      __syncthreads();
      u64 m = pmx[0];
      if (pmx[1] > m) m = pmx[1];
      if (pmx[2] > m) m = pmx[2];
      k = 4095 - (int)(m & 0xFFFull);
    }

    // ===== E: decision (replicated; ordering provided by D/A barriers) =====
    bool stop = (k == 0) || (sa >= MAX_SYM);
    if (!stop){
      if (wg == 0 && tid == 0) out[(size_t)NSTEPS*VOCAB + cnt] = (float)k;
      if (tid < 4){ c0c[tid] = c0p[tid]; c1c[tid] = c1p[tid]; }
      cnt++; sa++; last = k; reuse = false;
    } else {
      sa = 0; t++; reuse = true;
      if (t >= timesteps) done = true;
    }
  }

  // labels tail (-1) and cnt
  size_t lab = (size_t)NSTEPS*VOCAB;
  int gidx = wg*NTHR + tid;
  for (int i = cnt + gidx; i < NSTEPS; i += NWG*NTHR) out[lab + i] = -1.f;
  if (wg == 0 && tid == 0) out[lab + NSTEPS] = (float)cnt;
}

extern "C" void kernel_launch(void* const* d_in, const int* in_sizes, int n_in,
                              void* d_out, int out_size, void* d_ws, size_t ws_size,
                              hipStream_t stream) {
  const float* enc  = (const float*)d_in[0];
  const int*   olen = (const int*)  d_in[1];
  const float* emb  = (const float*)d_in[2];
  const float* Wih0 = (const float*)d_in[3];
  const float* Whh0 = (const float*)d_in[4];
  const float* b0   = (const float*)d_in[5];
  const float* Wih1 = (const float*)d_in[6];
  const float* Whh1 = (const float*)d_in[7];
  const float* b1   = (const float*)d_in[8];
  const float* Wj1  = (const float*)d_in[9];
  const float* bj1  = (const float*)d_in[10];
  const float* Wj2  = (const float*)d_in[11];
  const float* bj2  = (const float*)d_in[12];
  float* out = (float*)d_out;
  char* ws = (char*)d_ws;

  init_ws<<<1, 256, 0, stream>>>((unsigned*)d_ws);

  void* args[] = {&enc,&olen,&emb,&Wih0,&Whh0,&b0,&Wih1,&Whh1,&b1,
                  &Wj1,&bj1,&Wj2,&bj2,&out,&ws};
  hipLaunchCooperativeKernel((const void*)rnnt_decode, dim3(NWG), dim3(NTHR),
                             args, 0, stream);
}